// Round 2
// baseline (1628.729 us; speedup 1.0000x reference)
//
#include <hip/hip_runtime.h>
#include <hip/hip_bf16.h>

typedef __hip_bfloat16 bf16;
typedef short short8 __attribute__((ext_vector_type(8)));
typedef short short4v __attribute__((ext_vector_type(4)));
typedef float floatx4 __attribute__((ext_vector_type(4)));

#define B_ 4
#define SD_ 2048
#define SE_ 2048
#define DM_ 1024
#define H_ 8
#define DFF_ 4096

__device__ __forceinline__ float b2f(bf16 v) { return __bfloat162float(v); }
__device__ __forceinline__ bf16 f2b(float v) { return __float2bfloat16(v); }
__device__ __forceinline__ short f2s(float v) { return __builtin_bit_cast(short, __float2bfloat16(v)); }

// load 8 consecutive fp32, round to bf16, pack to short8
__device__ __forceinline__ short8 cvt8(const float* __restrict__ p) {
    floatx4 a = *(const floatx4*)p;
    floatx4 b = *(const floatx4*)(p + 4);
    short8 r;
#pragma unroll
    for (int i = 0; i < 4; ++i) {
        r[i]     = f2s(a[i]);
        r[i + 4] = f2s(b[i]);
    }
    return r;
}

// ---------------------------------------------------------------------------
// GEMM: C[M,N] = act(A[M,K] @ W[N,K]^T + bias[N]).
// A/W may be fp32 (converted to bf16 during LDS staging) or bf16. bias fp32.
// 128x128 tile, BK=64, 4 waves x (4x4) 16x16x32 bf16 MFMAs.
// LDS row stride 72: stride-64 would give 16-way bank conflicts on fragment
// reads; 72 gives 2-way (free per m136).
// ---------------------------------------------------------------------------
template <int A32, int W32, int RELU>
__global__ __launch_bounds__(256) void gemm_bt(
    const void* __restrict__ Ap, const void* __restrict__ Wp,
    const float* __restrict__ bias, bf16* __restrict__ C,
    int M, int N, int K)
{
    __shared__ __align__(16) short As[128][72];
    __shared__ __align__(16) short Ws[128][72];

    const int tid  = threadIdx.x;
    const int lane = tid & 63;
    const int wave = tid >> 6;
    const int quad = lane >> 4;
    const int l16  = lane & 15;
    const int bm0  = blockIdx.y * 128;
    const int bn0  = blockIdx.x * 128;
    const int wm   = (wave >> 1) * 64;
    const int wn   = (wave & 1) * 64;

    floatx4 acc[4][4];
#pragma unroll
    for (int i = 0; i < 4; ++i)
#pragma unroll
        for (int j = 0; j < 4; ++j)
            acc[i][j] = (floatx4){0.f, 0.f, 0.f, 0.f};

    const int srow = tid >> 3;        // 0..31
    const int scol = (tid & 7) * 8;   // 0..56

    for (int k0 = 0; k0 < K; k0 += 64) {
        __syncthreads();
#pragma unroll
        for (int r = 0; r < 4; ++r) {
            int row = r * 32 + srow;
            if (A32)
                *(short8*)&As[row][scol] =
                    cvt8((const float*)Ap + (size_t)(bm0 + row) * K + k0 + scol);
            else
                *(short8*)&As[row][scol] =
                    *(const short8*)((const bf16*)Ap + (size_t)(bm0 + row) * K + k0 + scol);
            if (W32)
                *(short8*)&Ws[row][scol] =
                    cvt8((const float*)Wp + (size_t)(bn0 + row) * K + k0 + scol);
            else
                *(short8*)&Ws[row][scol] =
                    *(const short8*)((const bf16*)Wp + (size_t)(bn0 + row) * K + k0 + scol);
        }
        __syncthreads();
#pragma unroll
        for (int kk = 0; kk < 64; kk += 32) {
            short8 af[4], bg[4];
#pragma unroll
            for (int i = 0; i < 4; ++i)
                af[i] = *(const short8*)&As[wm + i * 16 + l16][kk + quad * 8];
#pragma unroll
            for (int j = 0; j < 4; ++j)
                bg[j] = *(const short8*)&Ws[wn + j * 16 + l16][kk + quad * 8];
#pragma unroll
            for (int i = 0; i < 4; ++i)
#pragma unroll
                for (int j = 0; j < 4; ++j)
                    acc[i][j] = __builtin_amdgcn_mfma_f32_16x16x32_bf16(
                        af[i], bg[j], acc[i][j], 0, 0, 0);
        }
    }

    // C/D layout: col=lane&15, row=quad*4+reg (m89/m91 verified)
#pragma unroll
    for (int j = 0; j < 4; ++j) {
        int col = bn0 + wn + j * 16 + l16;
        float bv = bias[col];
#pragma unroll
        for (int i = 0; i < 4; ++i) {
            int row0 = bm0 + wm + i * 16 + quad * 4;
#pragma unroll
            for (int r = 0; r < 4; ++r) {
                float v = acc[i][j][r] + bv;
                if (RELU) v = fmaxf(v, 0.f);
                C[(size_t)(row0 + r) * N + col] = f2b(v);
            }
        }
    }
}

// ---------------------------------------------------------------------------
// Flash attention.  Q,K,V,O layout [B, S, H, 128] bf16.  One block = one
// (b,h) x 64 Q rows; 4 waves x 16 Q rows.  32-key chunks staged in LDS.
// Online softmax in MFMA C-layout; P -> A-layout via wave-private LDS.
// ---------------------------------------------------------------------------
template <int CAUSAL>
__global__ __launch_bounds__(256) void flash_attn(
    const bf16* __restrict__ Q, const bf16* __restrict__ K,
    const bf16* __restrict__ V, const int* __restrict__ pad,
    bf16* __restrict__ O, int Sq, int Sk)
{
    const int D = 128;
    __shared__ __align__(16) short Ks[32][136];
    __shared__ __align__(16) short Vs[32][132];
    __shared__ __align__(16) short Ps[4][16][40];

    const int tid  = threadIdx.x;
    const int lane = tid & 63;
    const int wave = tid >> 6;
    const int quad = lane >> 4;
    const int l16  = lane & 15;
    const int b    = blockIdx.y >> 3;
    const int h    = blockIdx.y & 7;
    const int q0   = blockIdx.x * 64;
    const int qw   = q0 + wave * 16;

    short8 qf[4];
    {
        const bf16* qbase = Q + ((size_t)(b * Sq + qw + l16) * H_ + h) * D;
#pragma unroll
        for (int c = 0; c < 4; ++c)
            qf[c] = *(const short8*)(qbase + c * 32 + quad * 8);
    }

    floatx4 o[8];
#pragma unroll
    for (int nf = 0; nf < 8; ++nf) o[nf] = (floatx4){0.f, 0.f, 0.f, 0.f};
    float mrow[4], lrow[4];
#pragma unroll
    for (int r = 0; r < 4; ++r) { mrow[r] = -1e30f; lrow[r] = 0.f; }

    const float scale = 0.08838834764831845f;  // 1/sqrt(128)
    int kEnd = Sk;
    if (CAUSAL && q0 + 64 < Sk) kEnd = q0 + 64;

    const int kr0  = tid >> 4;         // 0..15
    const int kcol = (tid & 15) * 8;   // 0..120

    for (int kc = 0; kc < kEnd; kc += 32) {
        __syncthreads();
#pragma unroll
        for (int r = 0; r < 2; ++r) {
            int kr = kr0 + r * 16;
            size_t gbase = ((size_t)(b * Sk + kc + kr) * H_ + h) * D + kcol;
            *(short8*)&Ks[kr][kcol] = *(const short8*)(K + gbase);
            short8 v8 = *(const short8*)(V + gbase);
            *(short4v*)&Vs[kr][kcol]     = __builtin_shufflevector(v8, v8, 0, 1, 2, 3);
            *(short4v*)&Vs[kr][kcol + 4] = __builtin_shufflevector(v8, v8, 4, 5, 6, 7);
        }
        __syncthreads();

        floatx4 sf[2];
#pragma unroll
        for (int f = 0; f < 2; ++f) {
            floatx4 s = (floatx4){0.f, 0.f, 0.f, 0.f};
#pragma unroll
            for (int c = 0; c < 4; ++c) {
                short8 kf = *(const short8*)&Ks[f * 16 + l16][c * 32 + quad * 8];
                s = __builtin_amdgcn_mfma_f32_16x16x32_bf16(qf[c], kf, s, 0, 0, 0);
            }
            sf[f] = s;
        }
#pragma unroll
        for (int f = 0; f < 2; ++f) {
            int kk = kc + f * 16 + l16;
            int pv = pad[b * Sk + kk];
#pragma unroll
            for (int r = 0; r < 4; ++r) {
                float sv = sf[f][r] * scale;
                bool ok = (pv != 0);
                if (CAUSAL) ok = ok && (kk <= qw + quad * 4 + r);
                sf[f][r] = ok ? sv : -1e30f;
            }
        }
        float al[4];
#pragma unroll
        for (int r = 0; r < 4; ++r) {
            float mx = fmaxf(sf[0][r], sf[1][r]);
#pragma unroll
            for (int off = 1; off < 16; off <<= 1)
                mx = fmaxf(mx, __shfl_xor(mx, off));
            float mn = fmaxf(mrow[r], mx);
            al[r] = __expf(mrow[r] - mn);
            mrow[r] = mn;
        }
#pragma unroll
        for (int f = 0; f < 2; ++f)
#pragma unroll
            for (int r = 0; r < 4; ++r)
                sf[f][r] = __expf(sf[f][r] - mrow[r]);
#pragma unroll
        for (int r = 0; r < 4; ++r) {
            float rs = sf[0][r] + sf[1][r];
#pragma unroll
            for (int off = 1; off < 16; off <<= 1)
                rs += __shfl_xor(rs, off);
            lrow[r] = lrow[r] * al[r] + rs;
        }
#pragma unroll
        for (int nf = 0; nf < 8; ++nf)
#pragma unroll
            for (int r = 0; r < 4; ++r)
                o[nf][r] *= al[r];

#pragma unroll
        for (int f = 0; f < 2; ++f)
#pragma unroll
            for (int r = 0; r < 4; ++r)
                Ps[wave][quad * 4 + r][f * 16 + l16] = f2s(sf[f][r]);
        __syncthreads();
        short8 pf = *(const short8*)&Ps[wave][l16][quad * 8];

#pragma unroll
        for (int nf = 0; nf < 8; ++nf) {
            short8 vf;
#pragma unroll
            for (int j = 0; j < 8; ++j)
                vf[j] = Vs[quad * 8 + j][nf * 16 + l16];
            o[nf] = __builtin_amdgcn_mfma_f32_16x16x32_bf16(pf, vf, o[nf], 0, 0, 0);
        }
    }

    float inv[4];
#pragma unroll
    for (int r = 0; r < 4; ++r) inv[r] = lrow[r] > 0.f ? 1.f / lrow[r] : 0.f;
#pragma unroll
    for (int nf = 0; nf < 8; ++nf)
#pragma unroll
        for (int r = 0; r < 4; ++r) {
            int q = qw + quad * 4 + r;
            O[((size_t)(b * Sq + q) * H_ + h) * D + nf * 16 + l16] =
                f2b(o[nf][r] * inv[r]);
        }
}

// ---------------------------------------------------------------------------
// out = LayerNorm(a + b) * g + beta.  A fp32 or bf16; out fp32 or bf16.
// B (the matmul branch) is always bf16; g/beta fp32; math fp32.
// ---------------------------------------------------------------------------
template <int A32, int O32>
__global__ __launch_bounds__(256) void add_ln(
    const void* __restrict__ Ap, const bf16* __restrict__ Bv,
    const float* __restrict__ g, const float* __restrict__ be,
    void* __restrict__ outp)
{
    const int D = DM_;
    __shared__ float red[8];
    const size_t row = blockIdx.x;
    const int t = threadIdx.x;

    float x[4];
    {
        float av[4];
        if (A32) {
            floatx4 a4 = *(const floatx4*)((const float*)Ap + row * D + t * 4);
#pragma unroll
            for (int i = 0; i < 4; ++i) av[i] = a4[i];
        } else {
            short4v a4 = *(const short4v*)((const bf16*)Ap + row * D + t * 4);
#pragma unroll
            for (int i = 0; i < 4; ++i)
                av[i] = b2f(__builtin_bit_cast(bf16, (short)a4[i]));
        }
        short4v b4 = *(const short4v*)(Bv + row * D + t * 4);
#pragma unroll
        for (int i = 0; i < 4; ++i)
            x[i] = av[i] + b2f(__builtin_bit_cast(bf16, (short)b4[i]));
    }
    float s = 0.f, s2 = 0.f;
#pragma unroll
    for (int i = 0; i < 4; ++i) { s += x[i]; s2 += x[i] * x[i]; }
#pragma unroll
    for (int off = 32; off >= 1; off >>= 1) {
        s  += __shfl_xor(s, off);
        s2 += __shfl_xor(s2, off);
    }
    const int wave = t >> 6;
    if ((t & 63) == 0) { red[wave] = s; red[4 + wave] = s2; }
    __syncthreads();
    s  = red[0] + red[1] + red[2] + red[3];
    s2 = red[4] + red[5] + red[6] + red[7];
    const float mu   = s * (1.f / D);
    const float var  = s2 * (1.f / D) - mu * mu;
    const float rstd = rsqrtf(var + 1e-5f);
#pragma unroll
    for (int i = 0; i < 4; ++i) {
        int idx = t * 4 + i;
        float v = (x[i] - mu) * rstd * g[idx] + be[idx];
        if (O32) ((float*)outp)[row * D + idx] = v;
        else     ((bf16*)outp)[row * D + idx] = f2b(v);
    }
}

// ---------------------------------------------------------------------------
extern "C" void kernel_launch(void* const* d_in, const int* in_sizes, int n_in,
                              void* d_out, int out_size, void* d_ws, size_t ws_size,
                              hipStream_t stream)
{
    const float* emb    = (const float*)d_in[0];
    const float* enc    = (const float*)d_in[1];
    const int*  in_pad  = (const int*)d_in[2];
    const int*  out_pad = (const int*)d_in[3];
    const float* q1_w = (const float*)d_in[4];  const float* q1_b = (const float*)d_in[5];
    const float* k1_w = (const float*)d_in[6];  const float* k1_b = (const float*)d_in[7];
    const float* v1_w = (const float*)d_in[8];  const float* v1_b = (const float*)d_in[9];
    const float* q2_w = (const float*)d_in[10]; const float* q2_b = (const float*)d_in[11];
    const float* k2_w = (const float*)d_in[12]; const float* k2_b = (const float*)d_in[13];
    const float* v2_w = (const float*)d_in[14]; const float* v2_b = (const float*)d_in[15];
    const float* sa_qw = (const float*)d_in[16]; const float* sa_qb = (const float*)d_in[17];
    const float* sa_kw = (const float*)d_in[18]; const float* sa_kb = (const float*)d_in[19];
    const float* sa_vw = (const float*)d_in[20]; const float* sa_vb = (const float*)d_in[21];
    const float* sa_ow = (const float*)d_in[22]; const float* sa_ob = (const float*)d_in[23];
    const float* ed_qw = (const float*)d_in[24]; const float* ed_qb = (const float*)d_in[25];
    const float* ed_kw = (const float*)d_in[26]; const float* ed_kb = (const float*)d_in[27];
    const float* ed_vw = (const float*)d_in[28]; const float* ed_vb = (const float*)d_in[29];
    const float* ed_ow = (const float*)d_in[30]; const float* ed_ob = (const float*)d_in[31];
    const float* ff_w1 = (const float*)d_in[32]; const float* ff_b1 = (const float*)d_in[33];
    const float* ff_w2 = (const float*)d_in[34]; const float* ff_b2 = (const float*)d_in[35];
    const float* ln1_g = (const float*)d_in[36]; const float* ln1_b = (const float*)d_in[37];
    const float* ln2_g = (const float*)d_in[38]; const float* ln2_b = (const float*)d_in[39];

    const int M = B_ * SD_;                 // 8192
    const size_t SLOT = (size_t)M * DM_;    // 8M bf16 elems = 16 MiB
    bf16* s[7];
    for (int i = 0; i < 7; ++i) s[i] = (bf16*)d_ws + SLOT * (size_t)i;
    // total workspace use: 7 * 16 MiB = 112 MiB (FF mid spans s[3..6])

    auto G = [&](auto a32, auto w32, auto relu, const void* Ai, const void* Wi,
                 const float* bi, bf16* Ci, int Mi, int Ni, int Ki) {
        dim3 grid(Ni / 128, Mi / 128);
        gemm_bt<decltype(a32)::value, decltype(w32)::value, decltype(relu)::value>
            <<<grid, 256, 0, stream>>>(Ai, Wi, bi, Ci, Mi, Ni, Ki);
    };
    using T = std::true_type; using F = std::false_type;

    // ---- self attention ----
    G(T{}, T{}, F{}, emb, q1_w, q1_b, s[0], M, DM_, DM_);   // Q
    G(T{}, T{}, F{}, emb, k1_w, k1_b, s[1], M, DM_, DM_);   // K
    G(T{}, T{}, F{}, emb, v1_w, v1_b, s[2], M, DM_, DM_);   // V
    G(F{}, T{}, F{}, s[0], sa_qw, sa_qb, s[3], M, DM_, DM_); // Qh
    G(F{}, T{}, F{}, s[1], sa_kw, sa_kb, s[4], M, DM_, DM_); // Kh
    G(F{}, T{}, F{}, s[2], sa_vw, sa_vb, s[5], M, DM_, DM_); // Vh
    flash_attn<1><<<dim3(SD_ / 64, B_ * H_), 256, 0, stream>>>(
        s[3], s[4], s[5], out_pad, s[0], SD_, SD_);
    G(F{}, T{}, F{}, s[0], sa_ow, sa_ob, s[1], M, DM_, DM_); // O-proj
    add_ln<1, 0><<<dim3(M), 256, 0, stream>>>(emb, s[1], ln1_g, ln1_b, s[2]); // x

    // ---- cross attention (residual from emb, per reference) ----
    G(F{}, T{}, F{}, s[2], q2_w, q2_b, s[0], M, DM_, DM_);   // Q2
    G(F{}, T{}, F{}, s[0], ed_qw, ed_qb, s[3], M, DM_, DM_); // Qh2
    G(T{}, T{}, F{}, enc, k2_w, k2_b, s[0], M, DM_, DM_);    // K2
    G(F{}, T{}, F{}, s[0], ed_kw, ed_kb, s[4], M, DM_, DM_); // Kh2
    G(T{}, T{}, F{}, enc, v2_w, v2_b, s[0], M, DM_, DM_);    // V2
    G(F{}, T{}, F{}, s[0], ed_vw, ed_vb, s[5], M, DM_, DM_); // Vh2
    flash_attn<0><<<dim3(SD_ / 64, B_ * H_), 256, 0, stream>>>(
        s[3], s[4], s[5], in_pad, s[0], SD_, SE_);
    G(F{}, T{}, F{}, s[0], ed_ow, ed_ob, s[1], M, DM_, DM_); // O-proj
    add_ln<1, 0><<<dim3(M), 256, 0, stream>>>(emb, s[1], ln2_g, ln2_b, s[2]); // y

    // ---- FFN (final norm reuses ln2 params, per reference) ----
    G(F{}, T{}, T{}, s[2], ff_w1, ff_b1, s[3], M, DFF_, DM_); // mid: s[3..6]
    G(F{}, T{}, F{}, s[3], ff_w2, ff_b2, s[0], M, DM_, DFF_);
    add_ln<0, 1><<<dim3(M), 256, 0, stream>>>(s[2], s[0], ln2_g, ln2_b, d_out);
}

// Round 3
// 1279.733 us; speedup vs baseline: 1.2727x; 1.2727x over previous
//
#include <hip/hip_runtime.h>
#include <hip/hip_bf16.h>

typedef __hip_bfloat16 bf16;
typedef short short8 __attribute__((ext_vector_type(8)));
typedef short short4v __attribute__((ext_vector_type(4)));
typedef float floatx4 __attribute__((ext_vector_type(4)));

#define B_ 4
#define SD_ 2048
#define SE_ 2048
#define DM_ 1024
#define H_ 8
#define DFF_ 4096

__device__ __forceinline__ float b2f(bf16 v) { return __bfloat162float(v); }
__device__ __forceinline__ bf16 f2b(float v) { return __float2bfloat16(v); }
__device__ __forceinline__ short f2s(float v) { return __builtin_bit_cast(short, __float2bfloat16(v)); }

// async global->LDS, 16B per lane. LDS dest = wave-uniform base + lane*16.
__device__ __forceinline__ void gl_lds16(const short* g, short* l) {
    __builtin_amdgcn_global_load_lds(
        (const __attribute__((address_space(1))) void*)g,
        (__attribute__((address_space(3))) void*)l, 16, 0, 0);
}

// ---------------------------------------------------------------------------
// fp32 -> bf16 conversion (vectorized, n multiple of 8)
// ---------------------------------------------------------------------------
__global__ __launch_bounds__(256) void cvt_f32_bf16(
    const float* __restrict__ in, bf16* __restrict__ out, int n)
{
    int i = (blockIdx.x * 256 + threadIdx.x) * 8;
    if (i >= n) return;
    floatx4 a = *(const floatx4*)(in + i);
    floatx4 b = *(const floatx4*)(in + i + 4);
    short8 r;
#pragma unroll
    for (int k = 0; k < 4; ++k) { r[k] = f2s(a[k]); r[k + 4] = f2s(b[k]); }
    *(short8*)(out + i) = r;
}

// ---------------------------------------------------------------------------
// GEMM: C[M,N] = act(A[M,K] @ W[N,K]^T + bias[N]).  A,W bf16; bias fp32.
// m97 recipe: global_load_lds dwordx4 staging, 128x128 tile, BK=64,
// 4 waves x (4x4) 16x16x32 MFMAs.  LDS: 16 segments of 8 rows x 64 shorts
// (1024 B, the contiguous unit global_load_lds requires) + 64 B pad between
// segments so fragment-read 16B-block positions are uniform mod 8 (no bank
// conflicts; stock m97 stride-64 had 16-way, counted by m98).
// ---------------------------------------------------------------------------
#define SEG_SH 544   // shorts per segment: 1024 B data + 64 B pad

template <int RELU>
__global__ __launch_bounds__(256) void gemm_bt(
    const bf16* __restrict__ A, const bf16* __restrict__ W,
    const float* __restrict__ bias, bf16* __restrict__ C,
    int M, int N, int K)
{
    __shared__ __align__(16) short As[16 * SEG_SH];
    __shared__ __align__(16) short Ws[16 * SEG_SH];

    const int tid  = threadIdx.x;
    const int lane = tid & 63;
    const int wave = tid >> 6;
    const int quad = lane >> 4;
    const int l16  = lane & 15;
    const int bm0  = blockIdx.y * 128;
    const int bn0  = blockIdx.x * 128;
    const int wm   = (wave >> 1) * 64;
    const int wn   = (wave & 1) * 64;

    // wave w stages segments w*4..w*4+3 (rows w*32 .. w*32+31)
    const short* Ag = (const short*)A + (size_t)(bm0 + wave * 32 + (lane >> 3)) * K + (lane & 7) * 8;
    const short* Wg = (const short*)W + (size_t)(bn0 + wave * 32 + (lane >> 3)) * K + (lane & 7) * 8;
    short* Al = As + (wave * 4) * SEG_SH;
    short* Wl = Ws + (wave * 4) * SEG_SH;

    floatx4 acc[4][4];
#pragma unroll
    for (int i = 0; i < 4; ++i)
#pragma unroll
        for (int j = 0; j < 4; ++j)
            acc[i][j] = (floatx4){0.f, 0.f, 0.f, 0.f};

    for (int k0 = 0; k0 < K; k0 += 64) {
        __syncthreads();
#pragma unroll
        for (int s = 0; s < 4; ++s) {
            gl_lds16(Ag + k0 + (size_t)s * 8 * K, Al + s * SEG_SH);
            gl_lds16(Wg + k0 + (size_t)s * 8 * K, Wl + s * SEG_SH);
        }
        __syncthreads();   // compiler drains vmcnt before s_barrier
#pragma unroll
        for (int kk = 0; kk < 64; kk += 32) {
            short8 af[4], bg[4];
#pragma unroll
            for (int i = 0; i < 4; ++i) {
                int row = wm + i * 16 + l16;
                af[i] = *(const short8*)&As[(row >> 3) * SEG_SH + (row & 7) * 64 + kk + quad * 8];
            }
#pragma unroll
            for (int j = 0; j < 4; ++j) {
                int row = wn + j * 16 + l16;
                bg[j] = *(const short8*)&Ws[(row >> 3) * SEG_SH + (row & 7) * 64 + kk + quad * 8];
            }
#pragma unroll
            for (int i = 0; i < 4; ++i)
#pragma unroll
                for (int j = 0; j < 4; ++j)
                    acc[i][j] = __builtin_amdgcn_mfma_f32_16x16x32_bf16(
                        af[i], bg[j], acc[i][j], 0, 0, 0);
        }
    }

    // C/D layout: col=lane&15, row=quad*4+reg (m89/m91)
#pragma unroll
    for (int j = 0; j < 4; ++j) {
        int col = bn0 + wn + j * 16 + l16;
        float bv = bias[col];
#pragma unroll
        for (int i = 0; i < 4; ++i) {
            int row0 = bm0 + wm + i * 16 + quad * 4;
#pragma unroll
            for (int r = 0; r < 4; ++r) {
                float v = acc[i][j][r] + bv;
                if (RELU) v = fmaxf(v, 0.f);
                C[(size_t)(row0 + r) * N + col] = f2b(v);
            }
        }
    }
}

// ---------------------------------------------------------------------------
// V transpose: in [B,S,H,128] -> out [B,H,128,S]  (per-(b,h) d-major)
// 32x32 tiles through LDS.
// ---------------------------------------------------------------------------
__global__ __launch_bounds__(256) void vtrans(
    const bf16* __restrict__ in, bf16* __restrict__ out, int S)
{
    __shared__ short t[32][36];
    const int tid = threadIdx.x;
    const int s0  = blockIdx.x * 32;
    const int d0  = blockIdx.y * 32;
    const int bh  = blockIdx.z;
    const int b = bh >> 3, h = bh & 7;
    const int i = tid >> 3;          // 0..31
    const int j = (tid & 7) * 4;     // 0..28

    *(short4v*)&t[i][j] =
        *(const short4v*)(in + ((size_t)(b * S + s0 + i) * H_ + h) * 128 + d0 + j);
    __syncthreads();
    short4v r;
#pragma unroll
    for (int p = 0; p < 4; ++p) r[p] = t[j + p][i];
    *(short4v*)(out + ((size_t)bh * 128 + d0 + i) * S + s0 + j) = r;
}

// ---------------------------------------------------------------------------
// Flash attention v2.  Q,K,O layout [B,S,H,128]; V pre-transposed [B,H,128,S].
// One block = one (b,h) x 128 Q rows; 4 waves x 32 rows (2 m-frags).
// K-chunk 64.  All LDS fragment traffic is aligned b128/b64 with uniform
// bank spread (stride 136/72/76 chosen from block-position arithmetic).
// ---------------------------------------------------------------------------
template <int CAUSAL>
__global__ __launch_bounds__(256) void flash_attn(
    const bf16* __restrict__ Q, const bf16* __restrict__ K,
    const bf16* __restrict__ Vt, const int* __restrict__ pad,
    bf16* __restrict__ O, int Sq, int Sk)
{
    __shared__ __align__(16) short Ks[64][136];
    __shared__ __align__(16) short Vs[128][72];
    __shared__ __align__(16) short Ps[4][32][76];

    const int tid  = threadIdx.x;
    const int lane = tid & 63;
    const int wave = tid >> 6;
    const int quad = lane >> 4;
    const int l16  = lane & 15;
    const int b    = blockIdx.y >> 3;
    const int h    = blockIdx.y & 7;
    const int q0   = blockIdx.x * 128;
    const int qw   = q0 + wave * 32;

    // Q fragments: 2 m-frags x 4 K-dim chunks (A-layout: m=lane&15, k=quad*8+j)
    short8 qf[2][4];
#pragma unroll
    for (int mi = 0; mi < 2; ++mi) {
        const bf16* qb = Q + ((size_t)(b * Sq + qw + mi * 16 + l16) * H_ + h) * 128;
#pragma unroll
        for (int c = 0; c < 4; ++c)
            qf[mi][c] = *(const short8*)(qb + c * 32 + quad * 8);
    }

    floatx4 o[2][8];
#pragma unroll
    for (int mi = 0; mi < 2; ++mi)
#pragma unroll
        for (int nf = 0; nf < 8; ++nf) o[mi][nf] = (floatx4){0.f, 0.f, 0.f, 0.f};
    float mrow[2][4], lrow[2][4];
#pragma unroll
    for (int mi = 0; mi < 2; ++mi)
#pragma unroll
        for (int r = 0; r < 4; ++r) { mrow[mi][r] = -1e30f; lrow[mi][r] = 0.f; }

    const float scale = 0.08838834764831845f;  // 1/sqrt(128)
    int kEnd = Sk;
    if (CAUSAL && q0 + 128 < Sk) kEnd = q0 + 128;

    const int krow = tid >> 4;         // 0..15
    const int kcol = (tid & 15) * 8;   // 0..120
    const int vn   = tid >> 1;         // 0..127
    const int vk0  = (tid & 1) * 32;

    for (int kc = 0; kc < kEnd; kc += 64) {
        __syncthreads();
        // stage K[64][128] (coalesced 16B) and Vt[128][64] (16B from d-major V)
#pragma unroll
        for (int rr = 0; rr < 4; ++rr) {
            int kr = rr * 16 + krow;
            *(short8*)&Ks[kr][kcol] =
                *(const short8*)(K + ((size_t)(b * Sk + kc + kr) * H_ + h) * 128 + kcol);
        }
#pragma unroll
        for (int jj = 0; jj < 4; ++jj)
            *(short8*)&Vs[vn][vk0 + jj * 8] =
                *(const short8*)(Vt + ((size_t)blockIdx.y * 128 + vn) * Sk + kc + vk0 + jj * 8);
        __syncthreads();

        // S = Q K^T  (C-layout: row=quad*4+r, col=l16)
        floatx4 sf[2][4];
#pragma unroll
        for (int f = 0; f < 4; ++f) {
            short8 kf[4];
#pragma unroll
            for (int c = 0; c < 4; ++c)
                kf[c] = *(const short8*)&Ks[f * 16 + l16][c * 32 + quad * 8];
#pragma unroll
            for (int mi = 0; mi < 2; ++mi) {
                floatx4 s = (floatx4){0.f, 0.f, 0.f, 0.f};
#pragma unroll
                for (int c = 0; c < 4; ++c)
                    s = __builtin_amdgcn_mfma_f32_16x16x32_bf16(qf[mi][c], kf[c], s, 0, 0, 0);
                sf[mi][f] = s;
            }
        }

        // mask + online softmax + P write, per m-frag
#pragma unroll
        for (int mi = 0; mi < 2; ++mi) {
#pragma unroll
            for (int f = 0; f < 4; ++f) {
                int kk = kc + f * 16 + l16;
                int pv = pad[b * Sk + kk];
#pragma unroll
                for (int r = 0; r < 4; ++r) {
                    float sv = sf[mi][f][r] * scale;
                    bool ok = (pv != 0);
                    if (CAUSAL) ok = ok && (kk <= qw + mi * 16 + quad * 4 + r);
                    sf[mi][f][r] = ok ? sv : -1e30f;
                }
            }
            float al[4];
#pragma unroll
            for (int r = 0; r < 4; ++r) {
                float mx = fmaxf(fmaxf(sf[mi][0][r], sf[mi][1][r]),
                                 fmaxf(sf[mi][2][r], sf[mi][3][r]));
#pragma unroll
                for (int off = 1; off < 16; off <<= 1)
                    mx = fmaxf(mx, __shfl_xor(mx, off));
                float mn = fmaxf(mrow[mi][r], mx);
                al[r] = __expf(mrow[mi][r] - mn);
                mrow[mi][r] = mn;
            }
#pragma unroll
            for (int f = 0; f < 4; ++f)
#pragma unroll
                for (int r = 0; r < 4; ++r)
                    sf[mi][f][r] = __expf(sf[mi][f][r] - mrow[mi][r]);
#pragma unroll
            for (int r = 0; r < 4; ++r) {
                float rs = sf[mi][0][r] + sf[mi][1][r] + sf[mi][2][r] + sf[mi][3][r];
#pragma unroll
                for (int off = 1; off < 16; off <<= 1)
                    rs += __shfl_xor(rs, off);
                lrow[mi][r] = lrow[mi][r] * al[r] + rs;
            }
#pragma unroll
            for (int nf = 0; nf < 8; ++nf)
#pragma unroll
                for (int r = 0; r < 4; ++r) o[mi][nf][r] *= al[r];
#pragma unroll
            for (int f = 0; f < 4; ++f)
#pragma unroll
                for (int r = 0; r < 4; ++r)
                    Ps[wave][mi * 16 + quad * 4 + r][f * 16 + l16] = f2s(sf[mi][f][r]);
        }
        // Ps is wave-private: compiler inserts lgkmcnt wait, no barrier needed.

        // O += P V  (P A-frags via 2x b64; V B-frags via aligned b128)
        short8 pf[2][2];
#pragma unroll
        for (int mi = 0; mi < 2; ++mi)
#pragma unroll
            for (int kk = 0; kk < 2; ++kk) {
                short4v lo = *(const short4v*)&Ps[wave][mi * 16 + l16][kk * 32 + quad * 8];
                short4v hi = *(const short4v*)&Ps[wave][mi * 16 + l16][kk * 32 + quad * 8 + 4];
                short8 p;
#pragma unroll
                for (int e = 0; e < 4; ++e) { p[e] = lo[e]; p[e + 4] = hi[e]; }
                pf[mi][kk] = p;
            }
#pragma unroll
        for (int nf = 0; nf < 8; ++nf) {
            short8 vfa[2];
#pragma unroll
            for (int kk = 0; kk < 2; ++kk)
                vfa[kk] = *(const short8*)&Vs[nf * 16 + l16][kk * 32 + quad * 8];
#pragma unroll
            for (int mi = 0; mi < 2; ++mi)
#pragma unroll
                for (int kk = 0; kk < 2; ++kk)
                    o[mi][nf] = __builtin_amdgcn_mfma_f32_16x16x32_bf16(
                        pf[mi][kk], vfa[kk], o[mi][nf], 0, 0, 0);
        }
    }

#pragma unroll
    for (int mi = 0; mi < 2; ++mi) {
        float inv[4];
#pragma unroll
        for (int r = 0; r < 4; ++r) inv[r] = lrow[mi][r] > 0.f ? 1.f / lrow[mi][r] : 0.f;
#pragma unroll
        for (int nf = 0; nf < 8; ++nf)
#pragma unroll
            for (int r = 0; r < 4; ++r) {
                int q = qw + mi * 16 + quad * 4 + r;
                O[((size_t)(b * Sq + q) * H_ + h) * 128 + nf * 16 + l16] =
                    f2b(o[mi][nf][r] * inv[r]);
            }
    }
}

// ---------------------------------------------------------------------------
// out = LayerNorm(a + b) * g + beta.  A fp32/bf16; out fp32/bf16; math fp32.
// ---------------------------------------------------------------------------
template <int A32, int O32>
__global__ __launch_bounds__(256) void add_ln(
    const void* __restrict__ Ap, const bf16* __restrict__ Bv,
    const float* __restrict__ g, const float* __restrict__ be,
    void* __restrict__ outp)
{
    const int D = DM_;
    __shared__ float red[8];
    const size_t row = blockIdx.x;
    const int t = threadIdx.x;

    float x[4];
    {
        float av[4];
        if (A32) {
            floatx4 a4 = *(const floatx4*)((const float*)Ap + row * D + t * 4);
#pragma unroll
            for (int i = 0; i < 4; ++i) av[i] = a4[i];
        } else {
            short4v a4 = *(const short4v*)((const bf16*)Ap + row * D + t * 4);
#pragma unroll
            for (int i = 0; i < 4; ++i)
                av[i] = b2f(__builtin_bit_cast(bf16, (short)a4[i]));
        }
        short4v b4 = *(const short4v*)(Bv + row * D + t * 4);
#pragma unroll
        for (int i = 0; i < 4; ++i)
            x[i] = av[i] + b2f(__builtin_bit_cast(bf16, (short)b4[i]));
    }
    float s = 0.f, s2 = 0.f;
#pragma unroll
    for (int i = 0; i < 4; ++i) { s += x[i]; s2 += x[i] * x[i]; }
#pragma unroll
    for (int off = 32; off >= 1; off >>= 1) {
        s  += __shfl_xor(s, off);
        s2 += __shfl_xor(s2, off);
    }
    const int wave = t >> 6;
    if ((t & 63) == 0) { red[wave] = s; red[4 + wave] = s2; }
    __syncthreads();
    s  = red[0] + red[1] + red[2] + red[3];
    s2 = red[4] + red[5] + red[6] + red[7];
    const float mu   = s * (1.f / D);
    const float var  = s2 * (1.f / D) - mu * mu;
    const float rstd = rsqrtf(var + 1e-5f);
#pragma unroll
    for (int i = 0; i < 4; ++i) {
        int idx = t * 4 + i;
        float v = (x[i] - mu) * rstd * g[idx] + be[idx];
        if (O32) ((float*)outp)[row * D + idx] = v;
        else     ((bf16*)outp)[row * D + idx] = f2b(v);
    }
}

// ---------------------------------------------------------------------------
extern "C" void kernel_launch(void* const* d_in, const int* in_sizes, int n_in,
                              void* d_out, int out_size, void* d_ws, size_t ws_size,
                              hipStream_t stream)
{
    const float* emb    = (const float*)d_in[0];
    const float* enc    = (const float*)d_in[1];
    const int*  in_pad  = (const int*)d_in[2];
    const int*  out_pad = (const int*)d_in[3];
    const float* q1_w = (const float*)d_in[4];  const float* q1_b = (const float*)d_in[5];
    const float* k1_w = (const float*)d_in[6];  const float* k1_b = (const float*)d_in[7];
    const float* v1_w = (const float*)d_in[8];  const float* v1_b = (const float*)d_in[9];
    const float* q2_w = (const float*)d_in[10]; const float* q2_b = (const float*)d_in[11];
    const float* k2_w = (const float*)d_in[12]; const float* k2_b = (const float*)d_in[13];
    const float* v2_w = (const float*)d_in[14]; const float* v2_b = (const float*)d_in[15];
    const float* sa_qw = (const float*)d_in[16]; const float* sa_qb = (const float*)d_in[17];
    const float* sa_kw = (const float*)d_in[18]; const float* sa_kb = (const float*)d_in[19];
    const float* sa_vw = (const float*)d_in[20]; const float* sa_vb = (const float*)d_in[21];
    const float* sa_ow = (const float*)d_in[22]; const float* sa_ob = (const float*)d_in[23];
    const float* ed_qw = (const float*)d_in[24]; const float* ed_qb = (const float*)d_in[25];
    const float* ed_kw = (const float*)d_in[26]; const float* ed_kb = (const float*)d_in[27];
    const float* ed_vw = (const float*)d_in[28]; const float* ed_vb = (const float*)d_in[29];
    const float* ed_ow = (const float*)d_in[30]; const float* ed_ob = (const float*)d_in[31];
    const float* ff_w1 = (const float*)d_in[32]; const float* ff_b1 = (const float*)d_in[33];
    const float* ff_w2 = (const float*)d_in[34]; const float* ff_b2 = (const float*)d_in[35];
    const float* ln1_g = (const float*)d_in[36]; const float* ln1_b = (const float*)d_in[37];
    const float* ln2_g = (const float*)d_in[38]; const float* ln2_b = (const float*)d_in[39];

    const int M = B_ * SD_;                 // 8192
    const size_t MM = (size_t)1024 * 1024;

    // workspace layout (bf16 elems):
    //   [0, 22M)   : 16 converted weights (14 x 1M + ff1 4M + ff2 4M)
    //   [22M, 78M) : 7 activation slots of 8M (16 MiB) each
    bf16* wb   = (bf16*)d_ws;
    bf16* s[7];
    for (int i = 0; i < 7; ++i) s[i] = wb + 22 * MM + (size_t)i * 8 * MM;

    const float* wsrc[16] = {q1_w, k1_w, v1_w, q2_w, k2_w, v2_w,
                             sa_qw, sa_kw, sa_vw, sa_ow,
                             ed_qw, ed_kw, ed_vw, ed_ow, ff_w1, ff_w2};
    bf16* wdst[16];
    {
        size_t off = 0;
        for (int i = 0; i < 16; ++i) {
            wdst[i] = wb + off;
            off += (i >= 14) ? 4 * MM : MM;
        }
    }
    for (int i = 0; i < 16; ++i) {
        int n = (i >= 14) ? (int)(4 * MM) : (int)MM;
        cvt_f32_bf16<<<dim3(n / 2048), 256, 0, stream>>>(wsrc[i], wdst[i], n);
    }
    bf16 *q1b = wdst[0], *k1b = wdst[1], *v1b = wdst[2], *q2b = wdst[3],
         *k2b = wdst[4], *v2b = wdst[5], *saqb = wdst[6], *sakb = wdst[7],
         *savb = wdst[8], *saob = wdst[9], *edqb = wdst[10], *edkb = wdst[11],
         *edvb = wdst[12], *edob = wdst[13], *ff1b = wdst[14], *ff2b = wdst[15];

    auto G = [&](const bf16* Ai, const bf16* Wi, const float* bi, bf16* Ci,
                 int Mi, int Ni, int Ki, bool relu) {
        dim3 grid(Ni / 128, Mi / 128);
        if (relu) gemm_bt<1><<<grid, 256, 0, stream>>>(Ai, Wi, bi, Ci, Mi, Ni, Ki);
        else      gemm_bt<0><<<grid, 256, 0, stream>>>(Ai, Wi, bi, Ci, Mi, Ni, Ki);
    };

    // ---- self attention ----
    cvt_f32_bf16<<<dim3(8 * MM / 2048), 256, 0, stream>>>(emb, s[6], (int)(8 * MM));
    G(s[6], q1b, q1_b, s[0], M, DM_, DM_, false);
    G(s[6], k1b, k1_b, s[1], M, DM_, DM_, false);
    G(s[6], v1b, v1_b, s[2], M, DM_, DM_, false);
    G(s[0], saqb, sa_qb, s[3], M, DM_, DM_, false);
    G(s[1], sakb, sa_kb, s[4], M, DM_, DM_, false);
    G(s[2], savb, sa_vb, s[5], M, DM_, DM_, false);
    vtrans<<<dim3(SD_ / 32, 4, B_ * H_), 256, 0, stream>>>(s[5], s[6], SD_);
    flash_attn<1><<<dim3(SD_ / 128, B_ * H_), 256, 0, stream>>>(
        s[3], s[4], s[6], out_pad, s[0], SD_, SD_);
    G(s[0], saob, sa_ob, s[1], M, DM_, DM_, false);
    add_ln<1, 0><<<dim3(M), 256, 0, stream>>>(emb, s[1], ln1_g, ln1_b, s[2]); // x

    // ---- cross attention (residual from emb, per reference) ----
    cvt_f32_bf16<<<dim3(8 * MM / 2048), 256, 0, stream>>>(enc, s[6], (int)(8 * MM));
    G(s[2], q2b, q2_b, s[0], M, DM_, DM_, false);
    G(s[0], edqb, ed_qb, s[3], M, DM_, DM_, false);
    G(s[6], k2b, k2_b, s[0], M, DM_, DM_, false);
    G(s[0], edkb, ed_kb, s[4], M, DM_, DM_, false);
    G(s[6], v2b, v2_b, s[0], M, DM_, DM_, false);
    G(s[0], edvb, ed_vb, s[1], M, DM_, DM_, false);
    vtrans<<<dim3(SE_ / 32, 4, B_ * H_), 256, 0, stream>>>(s[1], s[5], SE_);
    flash_attn<0><<<dim3(SD_ / 128, B_ * H_), 256, 0, stream>>>(
        s[3], s[4], s[5], in_pad, s[0], SD_, SE_);
    G(s[0], edob, ed_ob, s[1], M, DM_, DM_, false);
    add_ln<1, 0><<<dim3(M), 256, 0, stream>>>(emb, s[1], ln2_g, ln2_b, s[2]); // y

    // ---- FFN (final norm reuses ln2 params, per reference) ----
    G(s[2], ff1b, ff_b1, s[3], M, DFF_, DM_, true);   // mid spans s[3..6]
    G(s[3], ff2b, ff_b2, s[0], M, DM_, DFF_, false);
    add_ln<0, 1><<<dim3(M), 256, 0, stream>>>(s[2], s[0], ln2_g, ln2_b, d_out);
}